// Round 4
// baseline (349.841 us; speedup 1.0000x reference)
//
#include <hip/hip_runtime.h>

// ---------------------------------------------------------------------------
// EncodedGCN, round 3: zero global atomics.
// Radix-bucket edges by dest>>7 (128 nodes/bucket): LDS histograms -> scan ->
// LDS-ranked scatter into bucket-grouped edge array {src|c_lo<<25, w}.
// Then deg/dinv, conv1 and conv2 aggregation all run one-block-per-bucket
// with LDS float accumulation (ds_add_f32) -- fully edge-parallel, coalesced.
// ---------------------------------------------------------------------------

#define NBLKA 256     // blocks in hist/scatter passes
#define BSH   7       // bucket shift -> 128 nodes per bucket
#define BNODES 128
#define MAXBK 784     // max buckets (n <= 100352)

__global__ void k_senc(const float* __restrict__ sv, const float* __restrict__ w1,
                       const float* __restrict__ b1, const float* __restrict__ w2,
                       const float* __restrict__ b2, float* __restrict__ senc) {
    __shared__ float hid[32];
    int j = threadIdx.x;
    if (j < 32) {
        float acc = b1[j];
        #pragma unroll 8
        for (int k = 0; k < 64; ++k) acc += sv[k] * w1[k * 32 + j];
        hid[j] = acc > 0.f ? acc : 0.f;
    }
    __syncthreads();
    if (j == 0) {
        float acc = b2[0];
        #pragma unroll 8
        for (int k = 0; k < 32; ++k) acc += hid[k] * w2[k];
        senc[0] = acc;
    }
}

// Pass A: per-(block,bucket) histogram via LDS atomics.
__global__ void k_hist(const int* __restrict__ ei, int* __restrict__ hist,
                       int E, int EPB, int NBK) {
    __shared__ int lh[MAXBK];
    for (int k = threadIdx.x; k < NBK; k += blockDim.x) lh[k] = 0;
    __syncthreads();
    int b = blockIdx.x;
    int e0 = b * EPB, e1 = min(E, e0 + EPB);
    for (int e = e0 + threadIdx.x; e < e1; e += blockDim.x)
        atomicAdd(&lh[ei[E + e] >> BSH], 1);
    __syncthreads();
    for (int k = threadIdx.x; k < NBK; k += blockDim.x)
        hist[(size_t)k * NBLKA + b] = lh[k];
}

// 3-kernel exclusive scan over the flat [NBK][NBLKA] histogram (in place).
__global__ void k_scan1(int* __restrict__ data, int* __restrict__ bsum, int nflat) {
    __shared__ int s[512];
    int i = blockIdx.x * 512 + threadIdx.x;
    int v = (i < nflat) ? data[i] : 0;
    s[threadIdx.x] = v;
    __syncthreads();
    for (int off = 1; off < 512; off <<= 1) {
        int tv = (threadIdx.x >= off) ? s[threadIdx.x - off] : 0;
        __syncthreads();
        if (threadIdx.x >= off) s[threadIdx.x] += tv;
        __syncthreads();
    }
    if (i < nflat) data[i] = s[threadIdx.x] - v;   // exclusive
    if (threadIdx.x == 511) bsum[blockIdx.x] = s[511];
}

__global__ void k_scan2(int* __restrict__ bsum, int nb) {
    __shared__ int s[512];
    int v = (threadIdx.x < nb) ? bsum[threadIdx.x] : 0;
    s[threadIdx.x] = v;
    __syncthreads();
    for (int off = 1; off < 512; off <<= 1) {
        int tv = (threadIdx.x >= off) ? s[threadIdx.x - off] : 0;
        __syncthreads();
        if (threadIdx.x >= off) s[threadIdx.x] += tv;
        __syncthreads();
    }
    if (threadIdx.x < nb) bsum[threadIdx.x] = s[threadIdx.x] - v;  // exclusive
}

__global__ void k_scan3(int* __restrict__ data, const int* __restrict__ bsum, int nflat) {
    int i = blockIdx.x * 512 + threadIdx.x;
    if (i < nflat) data[i] += bsum[i >> 9];
}

// Pass C: scatter edges into bucket-grouped array; rank via LDS cursor.
__global__ void k_scatter(const int* __restrict__ ei, const float* __restrict__ ew,
                          const int* __restrict__ scanned, int2* __restrict__ ebuf,
                          int E, int EPB, int NBK) {
    __shared__ int lbase[MAXBK];
    int b = blockIdx.x;
    for (int k = threadIdx.x; k < NBK; k += blockDim.x)
        lbase[k] = scanned[(size_t)k * NBLKA + b];
    __syncthreads();
    int e0 = b * EPB, e1 = min(E, e0 + EPB);
    for (int e = e0 + threadIdx.x; e < e1; e += blockDim.x) {
        int c = ei[E + e];
        int r = ei[e];
        int k = c >> BSH;
        int pos = atomicAdd(&lbase[k], 1);          // LDS cursor = base+rank
        ebuf[pos] = make_int2(r | ((c & (BNODES - 1)) << 25), __float_as_int(ew[e]));
    }
}

// deg/dinv per bucket, LDS accumulation.
__global__ void k_deg(const int* __restrict__ scanned, const int2* __restrict__ ebuf,
                      float* __restrict__ dinv, int n, int E, int NBK) {
    __shared__ float sdeg[BNODES];
    int k = blockIdx.x;
    if (threadIdx.x < BNODES) sdeg[threadIdx.x] = 1.0f;  // self-loop
    __syncthreads();
    int bs = scanned[(size_t)k * NBLKA];
    int be = (k + 1 < NBK) ? scanned[(size_t)(k + 1) * NBLKA] : E;
    for (int s = bs + threadIdx.x; s < be; s += blockDim.x) {
        int2 ent = ebuf[s];
        atomicAdd(&sdeg[((unsigned)ent.x) >> 25], __int_as_float(ent.y));
    }
    __syncthreads();
    int i = k * BNODES + threadIdx.x;
    if (threadIdx.x < BNODES && i < n) dinv[i] = rsqrtf(sdeg[threadIdx.x]);
}

// conv1: agg9 in LDS (stride 9, odd -> bank-spread) + W1 + lrelu + W2 -> t.
__global__ void k_pass1(const int* __restrict__ scanned, const int2* __restrict__ ebuf,
                        const float* __restrict__ dinv, const float* __restrict__ x,
                        const float* __restrict__ senc,
                        const float* __restrict__ W1, const float* __restrict__ b1,
                        const float* __restrict__ W2, float* __restrict__ t,
                        int n, int E, int NBK) {
    __shared__ float sW1[288];
    __shared__ float sb1[32];
    __shared__ float sW2[512];
    __shared__ float sdinv[BNODES];
    __shared__ float acc[BNODES * 9];
    int k = blockIdx.x;
    for (int j = threadIdx.x; j < 288; j += blockDim.x) sW1[j] = W1[j];
    for (int j = threadIdx.x; j < 512; j += blockDim.x) sW2[j] = W2[j];
    if (threadIdx.x < 32) sb1[threadIdx.x] = b1[threadIdx.x];
    int c = threadIdx.x;
    if (c < BNODES) {
        int i = k * BNODES + c;
        float di = (i < n) ? dinv[i] : 0.f;
        sdinv[c] = di;
        float d2 = di * di;
        float4 u = make_float4(0.f, 0.f, 0.f, 0.f), v = u;
        if (i < n) {
            const float4* xi = reinterpret_cast<const float4*>(x + (size_t)i * 8);
            u = xi[0]; v = xi[1];
        }
        float* a = acc + c * 9;
        a[0] = d2 * u.x; a[1] = d2 * u.y; a[2] = d2 * u.z; a[3] = d2 * u.w;
        a[4] = d2 * v.x; a[5] = d2 * v.y; a[6] = d2 * v.z; a[7] = d2 * v.w;
        a[8] = d2;   // coefficient of constant senc column
    }
    __syncthreads();
    int bs = scanned[(size_t)k * NBLKA];
    int be = (k + 1 < NBK) ? scanned[(size_t)(k + 1) * NBLKA] : E;
    for (int s = bs + threadIdx.x; s < be; s += blockDim.x) {
        int2 ent = ebuf[s];
        int r = ent.x & 0x01FFFFFF;
        int cl = ((unsigned)ent.x) >> 25;
        float nrm = dinv[r] * __int_as_float(ent.y) * sdinv[cl];
        const float4* xr = reinterpret_cast<const float4*>(x + (size_t)r * 8);
        float4 p = xr[0], q = xr[1];
        float* a = acc + cl * 9;
        atomicAdd(a + 0, nrm * p.x); atomicAdd(a + 1, nrm * p.y);
        atomicAdd(a + 2, nrm * p.z); atomicAdd(a + 3, nrm * p.w);
        atomicAdd(a + 4, nrm * q.x); atomicAdd(a + 5, nrm * q.y);
        atomicAdd(a + 6, nrm * q.z); atomicAdd(a + 7, nrm * q.w);
        atomicAdd(a + 8, nrm);
    }
    __syncthreads();
    if (c < BNODES) {
        int i = k * BNODES + c;
        if (i < n) {
            float se = senc[0];
            const float* a = acc + c * 9;
            float a8 = a[8] * se;
            float h[32];
            #pragma unroll
            for (int j = 0; j < 32; ++j) {
                float v2 = sb1[j] + a8 * sW1[8 * 32 + j];
                #pragma unroll
                for (int f = 0; f < 8; ++f) v2 += a[f] * sW1[f * 32 + j];
                h[j] = v2 > 0.f ? v2 : 0.01f * v2;
            }
            float* ti = t + (size_t)i * 16;
            #pragma unroll
            for (int q2 = 0; q2 < 16; ++q2) {
                float v2 = 0.f;
                #pragma unroll
                for (int j = 0; j < 32; ++j) v2 += h[j] * sW2[j * 16 + q2];
                ti[q2] = v2;
            }
        }
    }
}

// conv2 agg in LDS (stride 17) + bias + lrelu + fc head -> out.
__global__ void k_pass2(const int* __restrict__ scanned, const int2* __restrict__ ebuf,
                        const float* __restrict__ dinv, const float* __restrict__ t,
                        const float* __restrict__ b2, const float* __restrict__ fw,
                        const float* __restrict__ fb, float* __restrict__ out,
                        int n, int E, int NBK) {
    __shared__ float sb2[16];
    __shared__ float sfw[16];
    __shared__ float sdinv[BNODES];
    __shared__ float acc[BNODES * 17];
    int k = blockIdx.x;
    if (threadIdx.x < 16) { sb2[threadIdx.x] = b2[threadIdx.x]; sfw[threadIdx.x] = fw[threadIdx.x]; }
    int c = threadIdx.x;
    if (c < BNODES) {
        int i = k * BNODES + c;
        float di = (i < n) ? dinv[i] : 0.f;
        sdinv[c] = di;
        float d2 = di * di;
        float* a = acc + c * 17;
        if (i < n) {
            const float4* ti = reinterpret_cast<const float4*>(t + (size_t)i * 16);
            #pragma unroll
            for (int q = 0; q < 4; ++q) {
                float4 u = ti[q];
                a[4 * q + 0] = d2 * u.x; a[4 * q + 1] = d2 * u.y;
                a[4 * q + 2] = d2 * u.z; a[4 * q + 3] = d2 * u.w;
            }
        } else {
            #pragma unroll
            for (int q = 0; q < 16; ++q) a[q] = 0.f;
        }
    }
    __syncthreads();
    int bs = scanned[(size_t)k * NBLKA];
    int be = (k + 1 < NBK) ? scanned[(size_t)(k + 1) * NBLKA] : E;
    for (int s = bs + threadIdx.x; s < be; s += blockDim.x) {
        int2 ent = ebuf[s];
        int r = ent.x & 0x01FFFFFF;
        int cl = ((unsigned)ent.x) >> 25;
        float nrm = dinv[r] * __int_as_float(ent.y) * sdinv[cl];
        const float4* tr = reinterpret_cast<const float4*>(t + (size_t)r * 16);
        float* a = acc + cl * 17;
        #pragma unroll
        for (int q = 0; q < 4; ++q) {
            float4 u = tr[q];
            atomicAdd(a + 4 * q + 0, nrm * u.x);
            atomicAdd(a + 4 * q + 1, nrm * u.y);
            atomicAdd(a + 4 * q + 2, nrm * u.z);
            atomicAdd(a + 4 * q + 3, nrm * u.w);
        }
    }
    __syncthreads();
    if (c < BNODES) {
        int i = k * BNODES + c;
        if (i < n) {
            const float* a = acc + c * 17;
            float o = fb[0];
            #pragma unroll
            for (int q = 0; q < 16; ++q) {
                float v = a[q] + sb2[q];
                v = v > 0.f ? v : 0.01f * v;
                o += v * sfw[q];
            }
            out[i] = o;
        }
    }
}

extern "C" void kernel_launch(void* const* d_in, const int* in_sizes, int n_in,
                              void* d_out, int out_size, void* d_ws, size_t ws_size,
                              hipStream_t stream) {
    const float* x      = (const float*)d_in[0];
    const int*   ei     = (const int*)d_in[1];
    const float* ew     = (const float*)d_in[2];
    const float* sv     = (const float*)d_in[3];
    const float* sfc1w  = (const float*)d_in[4];
    const float* sfc1b  = (const float*)d_in[5];
    const float* sfc2w  = (const float*)d_in[6];
    const float* sfc2b  = (const float*)d_in[7];
    const float* conv1w = (const float*)d_in[8];
    const float* conv1b = (const float*)d_in[9];
    const float* conv2w = (const float*)d_in[10];
    const float* conv2b = (const float*)d_in[11];
    const float* fc1w   = (const float*)d_in[12];
    const float* fc1b   = (const float*)d_in[13];

    const int n = in_sizes[0] / 8;
    const int E = in_sizes[2];

    const int NBK   = (n + BNODES - 1) >> BSH;          // buckets (<= MAXBK)
    const int nflat = NBK * NBLKA;                      // flat histogram size
    const int EPB   = (E + NBLKA - 1) / NBLKA;          // edges per hist block
    const int nb1   = (nflat + 511) / 512;              // scan1 blocks (<=512)

    // workspace layout (4-byte words, 16B-aligned segments)
    size_t off = 0;
    auto alloc = [&](size_t words) { size_t o = off; off += (words + 3) & ~(size_t)3; return o; };
    float* base  = (float*)d_ws;
    float* senc  = base + alloc(4);
    float* dinv  = base + alloc(n);
    int*   hist  = (int*)(base + alloc(nflat));
    int*   bsum  = (int*)(base + alloc(512));
    int2*  ebuf  = (int2*)(base + alloc((size_t)2 * E));
    float* tbuf  = base + alloc((size_t)16 * n);

    k_senc<<<1, 64, 0, stream>>>(sv, sfc1w, sfc1b, sfc2w, sfc2b, senc);
    k_hist<<<NBLKA, 256, 0, stream>>>(ei, hist, E, EPB, NBK);
    k_scan1<<<nb1, 512, 0, stream>>>(hist, bsum, nflat);
    k_scan2<<<1, 512, 0, stream>>>(bsum, nb1);
    k_scan3<<<nb1, 512, 0, stream>>>(hist, bsum, nflat);
    k_scatter<<<NBLKA, 256, 0, stream>>>(ei, ew, hist, ebuf, E, EPB, NBK);
    k_deg<<<NBK, 256, 0, stream>>>(hist, ebuf, dinv, n, E, NBK);
    k_pass1<<<NBK, 256, 0, stream>>>(hist, ebuf, dinv, x, senc,
                                     conv1w, conv1b, conv2w, tbuf, n, E, NBK);
    k_pass2<<<NBK, 256, 0, stream>>>(hist, ebuf, dinv, tbuf,
                                     conv2b, fc1w, fc1b, (float*)d_out, n, E, NBK);
}

// Round 5
// 167.401 us; speedup vs baseline: 2.0898x; 2.0898x over previous
//
#include <hip/hip_runtime.h>

// ---------------------------------------------------------------------------
// EncodedGCN, round 4: atomic-free CSR build (radix bucket + per-bucket
// counting sort), then round-2-style per-node register-gather passes.
//   hist(dest>>7, LDS) -> scan -> scatter(bucket-grouped, LDS cursors)
//   -> sort(one block/bucket: counts+wdeg in LDS, scan -> row[], dinv, CSR)
//   -> pass1 (agg9 gather + W1 + lrelu + W2 -> t)
//   -> pass2 (agg16 gather + b2 + lrelu + fc -> out), nrm recomputed.
// ---------------------------------------------------------------------------

#define NBLKA  256    // blocks in hist/scatter passes
#define BSH    7      // bucket shift -> 128 nodes/bucket
#define BNODES 128
#define MAXBK  784    // max buckets (n <= 100352)

__global__ void k_senc(const float* __restrict__ sv, const float* __restrict__ w1,
                       const float* __restrict__ b1, const float* __restrict__ w2,
                       const float* __restrict__ b2, float* __restrict__ senc) {
    __shared__ float hid[32];
    int j = threadIdx.x;
    if (j < 32) {
        float acc = b1[j];
        #pragma unroll 8
        for (int k = 0; k < 64; ++k) acc += sv[k] * w1[k * 32 + j];
        hid[j] = acc > 0.f ? acc : 0.f;
    }
    __syncthreads();
    if (j == 0) {
        float acc = b2[0];
        #pragma unroll 8
        for (int k = 0; k < 32; ++k) acc += hid[k] * w2[k];
        senc[0] = acc;
    }
}

__global__ void k_hist(const int* __restrict__ ei, int* __restrict__ hist,
                       int E, int EPB, int NBK) {
    __shared__ int lh[MAXBK];
    for (int k = threadIdx.x; k < NBK; k += blockDim.x) lh[k] = 0;
    __syncthreads();
    int b = blockIdx.x;
    int e0 = b * EPB, e1 = min(E, e0 + EPB);
    for (int e = e0 + threadIdx.x; e < e1; e += blockDim.x)
        atomicAdd(&lh[ei[E + e] >> BSH], 1);
    __syncthreads();
    for (int k = threadIdx.x; k < NBK; k += blockDim.x)
        hist[(size_t)k * NBLKA + b] = lh[k];
}

__global__ void k_scan1(int* __restrict__ data, int* __restrict__ bsum, int nflat) {
    __shared__ int s[512];
    int i = blockIdx.x * 512 + threadIdx.x;
    int v = (i < nflat) ? data[i] : 0;
    s[threadIdx.x] = v;
    __syncthreads();
    for (int off = 1; off < 512; off <<= 1) {
        int tv = (threadIdx.x >= off) ? s[threadIdx.x - off] : 0;
        __syncthreads();
        if (threadIdx.x >= off) s[threadIdx.x] += tv;
        __syncthreads();
    }
    if (i < nflat) data[i] = s[threadIdx.x] - v;   // exclusive
    if (threadIdx.x == 511) bsum[blockIdx.x] = s[511];
}

__global__ void k_scan2(int* __restrict__ bsum, int nb) {
    __shared__ int s[512];
    int v = (threadIdx.x < nb) ? bsum[threadIdx.x] : 0;
    s[threadIdx.x] = v;
    __syncthreads();
    for (int off = 1; off < 512; off <<= 1) {
        int tv = (threadIdx.x >= off) ? s[threadIdx.x - off] : 0;
        __syncthreads();
        if (threadIdx.x >= off) s[threadIdx.x] += tv;
        __syncthreads();
    }
    if (threadIdx.x < nb) bsum[threadIdx.x] = s[threadIdx.x] - v;  // exclusive
}

__global__ void k_scan3(int* __restrict__ data, const int* __restrict__ bsum, int nflat) {
    int i = blockIdx.x * 512 + threadIdx.x;
    if (i < nflat) data[i] += bsum[i >> 9];
}

// scatter edges into bucket-grouped ebuf {src | c_lo<<25, w}; LDS cursors.
__global__ void k_scatter(const int* __restrict__ ei, const float* __restrict__ ew,
                          const int* __restrict__ scanned, int2* __restrict__ ebuf,
                          int E, int EPB, int NBK) {
    __shared__ int lbase[MAXBK];
    int b = blockIdx.x;
    for (int k = threadIdx.x; k < NBK; k += blockDim.x)
        lbase[k] = scanned[(size_t)k * NBLKA + b];
    __syncthreads();
    int e0 = b * EPB, e1 = min(E, e0 + EPB);
    for (int e = e0 + threadIdx.x; e < e1; e += blockDim.x) {
        int c = ei[E + e];
        int r = ei[e];
        int k = c >> BSH;
        int pos = atomicAdd(&lbase[k], 1);
        ebuf[pos] = make_int2(r | ((c & (BNODES - 1)) << 25), __float_as_int(ew[e]));
    }
}

// one block per bucket: counting sort by local dest -> row[], dinv[], CSR.
__global__ void k_sort(const int* __restrict__ scanned, const int2* __restrict__ ebuf,
                       int* __restrict__ row, float* __restrict__ dinv,
                       int2* __restrict__ csr, int n, int E, int NBK) {
    __shared__ int lcnt[BNODES];
    __shared__ int lofs[BNODES];
    __shared__ float lw[BNODES];
    int k = blockIdx.x;
    if (threadIdx.x < BNODES) { lcnt[threadIdx.x] = 0; lw[threadIdx.x] = 1.0f; }  // self-loop
    __syncthreads();
    int bs = scanned[(size_t)k * NBLKA];
    int be = (k + 1 < NBK) ? scanned[(size_t)(k + 1) * NBLKA] : E;
    for (int s = bs + threadIdx.x; s < be; s += blockDim.x) {
        int2 ent = ebuf[s];
        int cl = ((unsigned)ent.x) >> 25;
        atomicAdd(&lcnt[cl], 1);
        atomicAdd(&lw[cl], __int_as_float(ent.y));
    }
    __syncthreads();
    // exclusive scan of lcnt (128) via Hillis-Steele; all threads hit barriers
    int v = (threadIdx.x < BNODES) ? lcnt[threadIdx.x] : 0;
    if (threadIdx.x < BNODES) lofs[threadIdx.x] = v;
    __syncthreads();
    for (int off = 1; off < BNODES; off <<= 1) {
        int tv = 0;
        if (threadIdx.x < BNODES && threadIdx.x >= off) tv = lofs[threadIdx.x - off];
        __syncthreads();
        if (threadIdx.x < BNODES && threadIdx.x >= off) lofs[threadIdx.x] += tv;
        __syncthreads();
    }
    if (threadIdx.x < BNODES) {
        int excl = lofs[threadIdx.x] - v;
        lofs[threadIdx.x] = excl;        // cursor base
        int i = k * BNODES + threadIdx.x;
        if (i < n) {
            row[i] = bs + excl;
            dinv[i] = rsqrtf(lw[threadIdx.x]);
        }
    }
    if (k == NBK - 1 && threadIdx.x == 0) row[n] = E;
    __syncthreads();
    for (int s = bs + threadIdx.x; s < be; s += blockDim.x) {
        int2 ent = ebuf[s];
        int cl = ((unsigned)ent.x) >> 25;
        int pos = bs + atomicAdd(&lofs[cl], 1);
        csr[pos] = make_int2(ent.x & 0x01FFFFFF, ent.y);
    }
}

// agg9 gather + conv1 + lrelu + conv2 -> t[i][16]
__global__ void k_pass1(const int* __restrict__ row, const int2* __restrict__ csr,
                        const float* __restrict__ dinv, const float* __restrict__ x,
                        const float* __restrict__ senc,
                        const float* __restrict__ W1, const float* __restrict__ b1,
                        const float* __restrict__ W2, float* __restrict__ t, int n) {
    __shared__ float sW1[288];
    __shared__ float sb1[32];
    __shared__ float sW2[512];
    for (int j = threadIdx.x; j < 288; j += blockDim.x) sW1[j] = W1[j];
    for (int j = threadIdx.x; j < 512; j += blockDim.x) sW2[j] = W2[j];
    if (threadIdx.x < 32) sb1[threadIdx.x] = b1[threadIdx.x];
    __syncthreads();
    int i = blockIdx.x * blockDim.x + threadIdx.x;
    if (i >= n) return;
    float di = dinv[i];
    float d2 = di * di;
    float a[8];
    const float4* xi = reinterpret_cast<const float4*>(x + (size_t)i * 8);
    float4 u = xi[0], v = xi[1];
    a[0] = d2 * u.x; a[1] = d2 * u.y; a[2] = d2 * u.z; a[3] = d2 * u.w;
    a[4] = d2 * v.x; a[5] = d2 * v.y; a[6] = d2 * v.z; a[7] = d2 * v.w;
    float wsum = d2;  // coefficient of constant senc column
    int s0 = row[i], s1 = row[i + 1];
    for (int s = s0; s < s1; ++s) {
        int2 ent = csr[s];
        int r = ent.x;
        float nrm = dinv[r] * __int_as_float(ent.y) * di;
        const float4* xr = reinterpret_cast<const float4*>(x + (size_t)r * 8);
        float4 p = xr[0], q = xr[1];
        a[0] += nrm * p.x; a[1] += nrm * p.y; a[2] += nrm * p.z; a[3] += nrm * p.w;
        a[4] += nrm * q.x; a[5] += nrm * q.y; a[6] += nrm * q.z; a[7] += nrm * q.w;
        wsum += nrm;
    }
    float a8 = wsum * senc[0];
    float h[32];
    #pragma unroll
    for (int j = 0; j < 32; ++j) {
        float acc = sb1[j] + a8 * sW1[8 * 32 + j];
        #pragma unroll
        for (int f = 0; f < 8; ++f) acc += a[f] * sW1[f * 32 + j];
        h[j] = acc > 0.f ? acc : 0.01f * acc;
    }
    float* ti = t + (size_t)i * 16;
    #pragma unroll
    for (int q2 = 0; q2 < 16; ++q2) {
        float acc = 0.f;
        #pragma unroll
        for (int j = 0; j < 32; ++j) acc += h[j] * sW2[j * 16 + q2];
        ti[q2] = acc;
    }
}

// agg16 gather + b2 + lrelu + fc -> out (nrm recomputed from dinv)
__global__ void k_pass2(const int* __restrict__ row, const int2* __restrict__ csr,
                        const float* __restrict__ dinv, const float* __restrict__ t,
                        const float* __restrict__ b2, const float* __restrict__ fw,
                        const float* __restrict__ fb, float* __restrict__ out, int n) {
    __shared__ float sb2[16];
    __shared__ float sfw[16];
    if (threadIdx.x < 16) { sb2[threadIdx.x] = b2[threadIdx.x]; sfw[threadIdx.x] = fw[threadIdx.x]; }
    __syncthreads();
    int i = blockIdx.x * blockDim.x + threadIdx.x;
    if (i >= n) return;
    float di = dinv[i];
    float d2 = di * di;
    float acc[16];
    const float4* ti = reinterpret_cast<const float4*>(t + (size_t)i * 16);
    #pragma unroll
    for (int q = 0; q < 4; ++q) {
        float4 u = ti[q];
        acc[4 * q + 0] = d2 * u.x; acc[4 * q + 1] = d2 * u.y;
        acc[4 * q + 2] = d2 * u.z; acc[4 * q + 3] = d2 * u.w;
    }
    int s0 = row[i], s1 = row[i + 1];
    for (int s = s0; s < s1; ++s) {
        int2 ent = csr[s];
        int r = ent.x;
        float nrm = dinv[r] * __int_as_float(ent.y) * di;
        const float4* tr = reinterpret_cast<const float4*>(t + (size_t)r * 16);
        #pragma unroll
        for (int q = 0; q < 4; ++q) {
            float4 u = tr[q];
            acc[4 * q + 0] += nrm * u.x; acc[4 * q + 1] += nrm * u.y;
            acc[4 * q + 2] += nrm * u.z; acc[4 * q + 3] += nrm * u.w;
        }
    }
    float o = fb[0];
    #pragma unroll
    for (int q = 0; q < 16; ++q) {
        float v = acc[q] + sb2[q];
        v = v > 0.f ? v : 0.01f * v;
        o += v * sfw[q];
    }
    out[i] = o;
}

extern "C" void kernel_launch(void* const* d_in, const int* in_sizes, int n_in,
                              void* d_out, int out_size, void* d_ws, size_t ws_size,
                              hipStream_t stream) {
    const float* x      = (const float*)d_in[0];
    const int*   ei     = (const int*)d_in[1];
    const float* ew     = (const float*)d_in[2];
    const float* sv     = (const float*)d_in[3];
    const float* sfc1w  = (const float*)d_in[4];
    const float* sfc1b  = (const float*)d_in[5];
    const float* sfc2w  = (const float*)d_in[6];
    const float* sfc2b  = (const float*)d_in[7];
    const float* conv1w = (const float*)d_in[8];
    const float* conv1b = (const float*)d_in[9];
    const float* conv2w = (const float*)d_in[10];
    const float* conv2b = (const float*)d_in[11];
    const float* fc1w   = (const float*)d_in[12];
    const float* fc1b   = (const float*)d_in[13];

    const int n = in_sizes[0] / 8;
    const int E = in_sizes[2];

    const int NBK   = (n + BNODES - 1) >> BSH;
    const int nflat = NBK * NBLKA;
    const int EPB   = (E + NBLKA - 1) / NBLKA;
    const int nb1   = (nflat + 511) / 512;

    // workspace layout (4-byte words, 16B-aligned segments)
    size_t off = 0;
    auto alloc = [&](size_t words) { size_t o = off; off += (words + 3) & ~(size_t)3; return o; };
    float* base  = (float*)d_ws;
    float* senc  = base + alloc(4);
    float* dinv  = base + alloc(n);
    int*   rowp  = (int*)(base + alloc(n + 1));
    int*   hist  = (int*)(base + alloc(nflat));
    int*   bsum  = (int*)(base + alloc(512));
    int2*  ebuf  = (int2*)(base + alloc((size_t)2 * E));
    int2*  csr   = (int2*)(base + alloc((size_t)2 * E));
    float* tbuf  = base + alloc((size_t)16 * n);

    const int BT = 256;
    const int gN = (n + BT - 1) / BT;

    k_senc<<<1, 64, 0, stream>>>(sv, sfc1w, sfc1b, sfc2w, sfc2b, senc);
    k_hist<<<NBLKA, 256, 0, stream>>>(ei, hist, E, EPB, NBK);
    k_scan1<<<nb1, 512, 0, stream>>>(hist, bsum, nflat);
    k_scan2<<<1, 512, 0, stream>>>(bsum, nb1);
    k_scan3<<<nb1, 512, 0, stream>>>(hist, bsum, nflat);
    k_scatter<<<NBLKA, 256, 0, stream>>>(ei, ew, hist, ebuf, E, EPB, NBK);
    k_sort<<<NBK, 256, 0, stream>>>(hist, ebuf, rowp, dinv, csr, n, E, NBK);
    k_pass1<<<gN, BT, 0, stream>>>(rowp, csr, dinv, x, senc,
                                   conv1w, conv1b, conv2w, tbuf, n);
    k_pass2<<<gN, BT, 0, stream>>>(rowp, csr, dinv, tbuf,
                                   conv2b, fc1w, fc1b, (float*)d_out, n);
}

// Round 6
// 147.453 us; speedup vs baseline: 2.3726x; 1.1353x over previous
//
#include <hip/hip_runtime.h>
#include <hip/hip_fp16.h>

// ---------------------------------------------------------------------------
// EncodedGCN, round 5: (a) t stored fp16 -> 3.2MB table fits per-XCD L2, so
// pass2's random row-gather stops missing to HBM; (b) edge lists split across
// lanes (pass1: 2/node, pass2: 4/node) + __shfl_xor merge -> 2-4x occupancy
// to hide gather latency. CSR build (hist/scan/scatter/sort) unchanged.
// ---------------------------------------------------------------------------

#define NBLKA  256
#define BSH    7
#define BNODES 128
#define MAXBK  784

__global__ void k_senc(const float* __restrict__ sv, const float* __restrict__ w1,
                       const float* __restrict__ b1, const float* __restrict__ w2,
                       const float* __restrict__ b2, float* __restrict__ senc) {
    __shared__ float hid[32];
    int j = threadIdx.x;
    if (j < 32) {
        float acc = b1[j];
        #pragma unroll 8
        for (int k = 0; k < 64; ++k) acc += sv[k] * w1[k * 32 + j];
        hid[j] = acc > 0.f ? acc : 0.f;
    }
    __syncthreads();
    if (j == 0) {
        float acc = b2[0];
        #pragma unroll 8
        for (int k = 0; k < 32; ++k) acc += hid[k] * w2[k];
        senc[0] = acc;
    }
}

__global__ void k_hist(const int* __restrict__ ei, int* __restrict__ hist,
                       int E, int EPB, int NBK) {
    __shared__ int lh[MAXBK];
    for (int k = threadIdx.x; k < NBK; k += blockDim.x) lh[k] = 0;
    __syncthreads();
    int b = blockIdx.x;
    int e0 = b * EPB, e1 = min(E, e0 + EPB);
    for (int e = e0 + threadIdx.x; e < e1; e += blockDim.x)
        atomicAdd(&lh[ei[E + e] >> BSH], 1);
    __syncthreads();
    for (int k = threadIdx.x; k < NBK; k += blockDim.x)
        hist[(size_t)k * NBLKA + b] = lh[k];
}

__global__ void k_scan1(int* __restrict__ data, int* __restrict__ bsum, int nflat) {
    __shared__ int s[512];
    int i = blockIdx.x * 512 + threadIdx.x;
    int v = (i < nflat) ? data[i] : 0;
    s[threadIdx.x] = v;
    __syncthreads();
    for (int off = 1; off < 512; off <<= 1) {
        int tv = (threadIdx.x >= off) ? s[threadIdx.x - off] : 0;
        __syncthreads();
        if (threadIdx.x >= off) s[threadIdx.x] += tv;
        __syncthreads();
    }
    if (i < nflat) data[i] = s[threadIdx.x] - v;
    if (threadIdx.x == 511) bsum[blockIdx.x] = s[511];
}

__global__ void k_scan2(int* __restrict__ bsum, int nb) {
    __shared__ int s[512];
    int v = (threadIdx.x < nb) ? bsum[threadIdx.x] : 0;
    s[threadIdx.x] = v;
    __syncthreads();
    for (int off = 1; off < 512; off <<= 1) {
        int tv = (threadIdx.x >= off) ? s[threadIdx.x - off] : 0;
        __syncthreads();
        if (threadIdx.x >= off) s[threadIdx.x] += tv;
        __syncthreads();
    }
    if (threadIdx.x < nb) bsum[threadIdx.x] = s[threadIdx.x] - v;
}

__global__ void k_scan3(int* __restrict__ data, const int* __restrict__ bsum, int nflat) {
    int i = blockIdx.x * 512 + threadIdx.x;
    if (i < nflat) data[i] += bsum[i >> 9];
}

__global__ void k_scatter(const int* __restrict__ ei, const float* __restrict__ ew,
                          const int* __restrict__ scanned, int2* __restrict__ ebuf,
                          int E, int EPB, int NBK) {
    __shared__ int lbase[MAXBK];
    int b = blockIdx.x;
    for (int k = threadIdx.x; k < NBK; k += blockDim.x)
        lbase[k] = scanned[(size_t)k * NBLKA + b];
    __syncthreads();
    int e0 = b * EPB, e1 = min(E, e0 + EPB);
    for (int e = e0 + threadIdx.x; e < e1; e += blockDim.x) {
        int c = ei[E + e];
        int r = ei[e];
        int k = c >> BSH;
        int pos = atomicAdd(&lbase[k], 1);
        ebuf[pos] = make_int2(r | ((c & (BNODES - 1)) << 25), __float_as_int(ew[e]));
    }
}

__global__ void k_sort(const int* __restrict__ scanned, const int2* __restrict__ ebuf,
                       int* __restrict__ row, float* __restrict__ dinv,
                       int2* __restrict__ csr, int n, int E, int NBK) {
    __shared__ int lcnt[BNODES];
    __shared__ int lofs[BNODES];
    __shared__ float lw[BNODES];
    int k = blockIdx.x;
    if (threadIdx.x < BNODES) { lcnt[threadIdx.x] = 0; lw[threadIdx.x] = 1.0f; }
    __syncthreads();
    int bs = scanned[(size_t)k * NBLKA];
    int be = (k + 1 < NBK) ? scanned[(size_t)(k + 1) * NBLKA] : E;
    for (int s = bs + threadIdx.x; s < be; s += blockDim.x) {
        int2 ent = ebuf[s];
        int cl = ((unsigned)ent.x) >> 25;
        atomicAdd(&lcnt[cl], 1);
        atomicAdd(&lw[cl], __int_as_float(ent.y));
    }
    __syncthreads();
    int v = (threadIdx.x < BNODES) ? lcnt[threadIdx.x] : 0;
    if (threadIdx.x < BNODES) lofs[threadIdx.x] = v;
    __syncthreads();
    for (int off = 1; off < BNODES; off <<= 1) {
        int tv = 0;
        if (threadIdx.x < BNODES && threadIdx.x >= off) tv = lofs[threadIdx.x - off];
        __syncthreads();
        if (threadIdx.x < BNODES && threadIdx.x >= off) lofs[threadIdx.x] += tv;
        __syncthreads();
    }
    if (threadIdx.x < BNODES) {
        int excl = lofs[threadIdx.x] - v;
        lofs[threadIdx.x] = excl;
        int i = k * BNODES + threadIdx.x;
        if (i < n) {
            row[i] = bs + excl;
            dinv[i] = rsqrtf(lw[threadIdx.x]);
        }
    }
    if (k == NBK - 1 && threadIdx.x == 0) row[n] = E;
    __syncthreads();
    for (int s = bs + threadIdx.x; s < be; s += blockDim.x) {
        int2 ent = ebuf[s];
        int cl = ((unsigned)ent.x) >> 25;
        int pos = bs + atomicAdd(&lofs[cl], 1);
        csr[pos] = make_int2(ent.x & 0x01FFFFFF, ent.y);
    }
}

// pass1, 2 lanes/node: agg9 gather + conv1 + lrelu + conv2 -> t (fp16)
__global__ void k_pass1(const int* __restrict__ row, const int2* __restrict__ csr,
                        const float* __restrict__ dinv, const float* __restrict__ x,
                        const float* __restrict__ senc,
                        const float* __restrict__ W1, const float* __restrict__ b1,
                        const float* __restrict__ W2, __half* __restrict__ th, int n) {
    __shared__ float sW1[288];
    __shared__ float sb1[32];
    __shared__ float sW2[512];
    for (int j = threadIdx.x; j < 288; j += blockDim.x) sW1[j] = W1[j];
    for (int j = threadIdx.x; j < 512; j += blockDim.x) sW2[j] = W2[j];
    if (threadIdx.x < 32) sb1[threadIdx.x] = b1[threadIdx.x];
    __syncthreads();
    int g = blockIdx.x * blockDim.x + threadIdx.x;
    int i = g >> 1;
    int half = g & 1;
    if (i >= n) return;
    float di = dinv[i];
    float a[8];
    float wsum;
    if (half == 0) {
        float d2 = di * di;
        const float4* xi = reinterpret_cast<const float4*>(x + (size_t)i * 8);
        float4 u = xi[0], v = xi[1];
        a[0] = d2 * u.x; a[1] = d2 * u.y; a[2] = d2 * u.z; a[3] = d2 * u.w;
        a[4] = d2 * v.x; a[5] = d2 * v.y; a[6] = d2 * v.z; a[7] = d2 * v.w;
        wsum = d2;
    } else {
        #pragma unroll
        for (int q = 0; q < 8; ++q) a[q] = 0.f;
        wsum = 0.f;
    }
    int s0 = row[i], s1 = row[i + 1];
    for (int s = s0 + half; s < s1; s += 2) {
        int2 ent = csr[s];
        int r = ent.x;
        float nrm = dinv[r] * __int_as_float(ent.y) * di;
        const float4* xr = reinterpret_cast<const float4*>(x + (size_t)r * 8);
        float4 p = xr[0], q = xr[1];
        a[0] += nrm * p.x; a[1] += nrm * p.y; a[2] += nrm * p.z; a[3] += nrm * p.w;
        a[4] += nrm * q.x; a[5] += nrm * q.y; a[6] += nrm * q.z; a[7] += nrm * q.w;
        wsum += nrm;
    }
    #pragma unroll
    for (int q = 0; q < 8; ++q) a[q] += __shfl_xor(a[q], 1);
    wsum += __shfl_xor(wsum, 1);
    if (half) return;
    float a8 = wsum * senc[0];
    float h[32];
    #pragma unroll
    for (int j = 0; j < 32; ++j) {
        float acc = sb1[j] + a8 * sW1[8 * 32 + j];
        #pragma unroll
        for (int f = 0; f < 8; ++f) acc += a[f] * sW1[f * 32 + j];
        h[j] = acc > 0.f ? acc : 0.01f * acc;
    }
    unsigned u[8];
    #pragma unroll
    for (int p2 = 0; p2 < 8; ++p2) {
        float t0 = 0.f, t1 = 0.f;
        #pragma unroll
        for (int j = 0; j < 32; ++j) {
            t0 += h[j] * sW2[j * 16 + 2 * p2];
            t1 += h[j] * sW2[j * 16 + 2 * p2 + 1];
        }
        __half2 hv = __floats2half2_rn(t0, t1);
        u[p2] = *reinterpret_cast<unsigned*>(&hv);
    }
    uint4* tp = reinterpret_cast<uint4*>(th + (size_t)i * 16);
    tp[0] = make_uint4(u[0], u[1], u[2], u[3]);
    tp[1] = make_uint4(u[4], u[5], u[6], u[7]);
}

// pass2, 4 lanes/node: agg16 gather (fp16 t, L2-resident) + b2 + lrelu + fc
__global__ void k_pass2(const int* __restrict__ row, const int2* __restrict__ csr,
                        const float* __restrict__ dinv, const __half* __restrict__ th,
                        const float* __restrict__ b2, const float* __restrict__ fw,
                        const float* __restrict__ fb, float* __restrict__ out, int n) {
    __shared__ float sb2[16];
    __shared__ float sfw[16];
    if (threadIdx.x < 16) { sb2[threadIdx.x] = b2[threadIdx.x]; sfw[threadIdx.x] = fw[threadIdx.x]; }
    __syncthreads();
    int g = blockIdx.x * blockDim.x + threadIdx.x;
    int i = g >> 2;
    int quad = g & 3;
    if (i >= n) return;
    float di = dinv[i];
    float acc[16];
    if (quad == 0) {
        float d2 = di * di;
        const uint4* tp = reinterpret_cast<const uint4*>(th + (size_t)i * 16);
        uint4 w0 = tp[0], w1 = tp[1];
        const __half2* hh0 = reinterpret_cast<const __half2*>(&w0);
        const __half2* hh1 = reinterpret_cast<const __half2*>(&w1);
        #pragma unroll
        for (int q = 0; q < 4; ++q) {
            float2 f0 = __half22float2(hh0[q]);
            float2 f1 = __half22float2(hh1[q]);
            acc[2 * q + 0] = d2 * f0.x; acc[2 * q + 1] = d2 * f0.y;
            acc[8 + 2 * q + 0] = d2 * f1.x; acc[8 + 2 * q + 1] = d2 * f1.y;
        }
    } else {
        #pragma unroll
        for (int q = 0; q < 16; ++q) acc[q] = 0.f;
    }
    int s0 = row[i], s1 = row[i + 1];
    for (int s = s0 + quad; s < s1; s += 4) {
        int2 ent = csr[s];
        int r = ent.x;
        float nrm = dinv[r] * __int_as_float(ent.y) * di;
        const uint4* tp = reinterpret_cast<const uint4*>(th + (size_t)r * 16);
        uint4 w0 = tp[0], w1 = tp[1];
        const __half2* hh0 = reinterpret_cast<const __half2*>(&w0);
        const __half2* hh1 = reinterpret_cast<const __half2*>(&w1);
        #pragma unroll
        for (int q = 0; q < 4; ++q) {
            float2 f0 = __half22float2(hh0[q]);
            float2 f1 = __half22float2(hh1[q]);
            acc[2 * q + 0] += nrm * f0.x; acc[2 * q + 1] += nrm * f0.y;
            acc[8 + 2 * q + 0] += nrm * f1.x; acc[8 + 2 * q + 1] += nrm * f1.y;
        }
    }
    #pragma unroll
    for (int q = 0; q < 16; ++q) acc[q] += __shfl_xor(acc[q], 1);
    #pragma unroll
    for (int q = 0; q < 16; ++q) acc[q] += __shfl_xor(acc[q], 2);
    if (quad) return;
    float o = fb[0];
    #pragma unroll
    for (int q = 0; q < 16; ++q) {
        float v = acc[q] + sb2[q];
        v = v > 0.f ? v : 0.01f * v;
        o += v * sfw[q];
    }
    out[i] = o;
}

extern "C" void kernel_launch(void* const* d_in, const int* in_sizes, int n_in,
                              void* d_out, int out_size, void* d_ws, size_t ws_size,
                              hipStream_t stream) {
    const float* x      = (const float*)d_in[0];
    const int*   ei     = (const int*)d_in[1];
    const float* ew     = (const float*)d_in[2];
    const float* sv     = (const float*)d_in[3];
    const float* sfc1w  = (const float*)d_in[4];
    const float* sfc1b  = (const float*)d_in[5];
    const float* sfc2w  = (const float*)d_in[6];
    const float* sfc2b  = (const float*)d_in[7];
    const float* conv1w = (const float*)d_in[8];
    const float* conv1b = (const float*)d_in[9];
    const float* conv2w = (const float*)d_in[10];
    const float* conv2b = (const float*)d_in[11];
    const float* fc1w   = (const float*)d_in[12];
    const float* fc1b   = (const float*)d_in[13];

    const int n = in_sizes[0] / 8;
    const int E = in_sizes[2];

    const int NBK   = (n + BNODES - 1) >> BSH;
    const int nflat = NBK * NBLKA;
    const int EPB   = (E + NBLKA - 1) / NBLKA;
    const int nb1   = (nflat + 511) / 512;

    size_t off = 0;
    auto alloc = [&](size_t words) { size_t o = off; off += (words + 3) & ~(size_t)3; return o; };
    float*  base = (float*)d_ws;
    float*  senc = base + alloc(4);
    float*  dinv = base + alloc(n);
    int*    rowp = (int*)(base + alloc(n + 1));
    int*    hist = (int*)(base + alloc(nflat));
    int*    bsum = (int*)(base + alloc(512));
    int2*   ebuf = (int2*)(base + alloc((size_t)2 * E));
    int2*   csr  = (int2*)(base + alloc((size_t)2 * E));
    __half* th   = (__half*)(base + alloc((size_t)8 * n));  // n*16 halfs

    const int BT = 256;
    const int g1 = ((size_t)2 * n + BT - 1) / BT;
    const int g2 = ((size_t)4 * n + BT - 1) / BT;

    k_senc<<<1, 64, 0, stream>>>(sv, sfc1w, sfc1b, sfc2w, sfc2b, senc);
    k_hist<<<NBLKA, 256, 0, stream>>>(ei, hist, E, EPB, NBK);
    k_scan1<<<nb1, 512, 0, stream>>>(hist, bsum, nflat);
    k_scan2<<<1, 512, 0, stream>>>(bsum, nb1);
    k_scan3<<<nb1, 512, 0, stream>>>(hist, bsum, nflat);
    k_scatter<<<NBLKA, 256, 0, stream>>>(ei, ew, hist, ebuf, E, EPB, NBK);
    k_sort<<<NBK, 256, 0, stream>>>(hist, ebuf, rowp, dinv, csr, n, E, NBK);
    k_pass1<<<g1, BT, 0, stream>>>(rowp, csr, dinv, x, senc,
                                   conv1w, conv1b, conv2w, th, n);
    k_pass2<<<g2, BT, 0, stream>>>(rowp, csr, dinv, th,
                                   conv2b, fc1w, fc1b, (float*)d_out, n);
}